// Round 1
// baseline (198.730 us; speedup 1.0000x reference)
//
#include <hip/hip_runtime.h>
#include <stdint.h>

// Problem constants (fixed by setup_inputs)
#define B_   8
#define S_   16
#define T_   128
#define D_   64
#define N_   2048               // S_*T_ tokens per batch
#define NEGV (-1000000000.0f)

typedef short s16x8 __attribute__((ext_vector_type(8)));   // 8 bf16 (4 VGPRs)
typedef float f32x4 __attribute__((ext_vector_type(4)));

static __device__ __forceinline__ unsigned short f2bf(float f) {
    unsigned u = __builtin_bit_cast(unsigned, f);
    u += 0x7FFFu + ((u >> 16) & 1u);            // RTNE
    return (unsigned short)(u >> 16);
}
static __device__ __forceinline__ float bf2f(unsigned short h) {
    unsigned u = ((unsigned)h) << 16;
    return __builtin_bit_cast(float, u);
}
static __device__ __forceinline__ s16x8 ldfrag_g(const unsigned short* p) {
    uint4 v = *(const uint4*)p;                 // global_load_dwordx4
    return __builtin_bit_cast(s16x8, v);
}
static __device__ __forceinline__ s16x8 ldfrag_l(const unsigned short* p) {
    uint4 v = *(const uint4*)p;                 // ds_read_b128
    return __builtin_bit_cast(s16x8, v);
}

// ---------------------------------------------------------------------------
// Kernel 1: QKV projection. x[f32] -> qb (scaled by 1/8), kb  [b][n][64] bf16,
// and v stored TRANSPOSED in the reference's quirky vf layout:
// vbT[b][dv][m], m = t*S + s  (so PV B-frags are contiguous 16B reads).
// One block = 64 tokens; MFMA 16x16x32 over concatenated W (q,k,v).
// ---------------------------------------------------------------------------
__global__ __launch_bounds__(256, 2) void proj_kernel(
    const float* __restrict__ x,
    const float* __restrict__ Wq, const float* __restrict__ bq,
    const float* __restrict__ Wk, const float* __restrict__ bk,
    const float* __restrict__ Wv, const float* __restrict__ bv,
    unsigned short* __restrict__ qb, unsigned short* __restrict__ kb,
    unsigned short* __restrict__ vbT)
{
    __shared__ unsigned short xs[64][72];    // +8 pad: conflict-light b128 reads
    __shared__ unsigned short Wl[192][72];   // rows: 0-63 Wq[j][i], 64-127 Wk, 128-191 Wv
    __shared__ float          biasl[192];

    const int tid = threadIdx.x;
    const int g0  = blockIdx.x * 64;         // first global token of block

    // Stage x tile (64x64 f32 -> bf16)
    const float4* xsrc = (const float4*)(x + (size_t)g0 * 64);
    #pragma unroll
    for (int k2 = 0; k2 < 4; ++k2) {
        int idx = tid + 256 * k2;            // float4 index, coalesced
        float4 v = xsrc[idx];
        int tok = idx >> 4, i4 = (idx & 15) * 4;
        uint2 pk;
        pk.x = (unsigned)f2bf(v.x) | ((unsigned)f2bf(v.y) << 16);
        pk.y = (unsigned)f2bf(v.z) | ((unsigned)f2bf(v.w) << 16);
        *(uint2*)&xs[tok][i4] = pk;
    }
    // Stage W (q,k,v) as-given layout [j][i] (this IS the B-frag-friendly layout)
    #pragma unroll
    for (int k2 = 0; k2 < 12; ++k2) {
        const float* wsrc = (k2 < 4) ? Wq : ((k2 < 8) ? Wk : Wv);
        int f4i = (k2 & 3) * 256 + tid;
        float4 v = ((const float4*)wsrc)[f4i];
        int j = f4i >> 4, i4 = (f4i & 15) * 4;
        int row = (k2 >> 2) * 64 + j;
        uint2 pk;
        pk.x = (unsigned)f2bf(v.x) | ((unsigned)f2bf(v.y) << 16);
        pk.y = (unsigned)f2bf(v.z) | ((unsigned)f2bf(v.w) << 16);
        *(uint2*)&Wl[row][i4] = pk;
    }
    if (tid < 192) {
        int m = tid >> 6;
        const float* bs = (m == 0) ? bq : (m == 1 ? bk : bv);
        biasl[tid] = bs[tid & 63];
    }
    __syncthreads();

    const int w = tid >> 6, lane = tid & 63;
    const int q = lane >> 4, l15 = lane & 15;

    #pragma unroll
    for (int e = 0; e < 3; ++e) {
        const int nt   = w * 3 + e;          // 12 N-subtiles of 16 across q|k|v
        const int matU = nt >> 2;            // 0=q 1=k 2=v (16 | 64, never splits)
        const float bsc = biasl[nt * 16 + l15];
        const float scl = (matU == 0) ? 0.125f : 1.0f;   // fold 1/sqrt(64) into q
        const int j = (nt & 3) * 16 + l15;   // output dim within its matrix
        unsigned short* dqk = (matU == 0) ? qb : kb;
        #pragma unroll
        for (int ms = 0; ms < 4; ++ms) {
            f32x4 acc = {0.f, 0.f, 0.f, 0.f};
            #pragma unroll
            for (int ks = 0; ks < 2; ++ks) {
                s16x8 a = ldfrag_l(&xs[ms * 16 + l15][ks * 32 + q * 8]);
                s16x8 b = ldfrag_l(&Wl[nt * 16 + l15][ks * 32 + q * 8]);
                acc = __builtin_amdgcn_mfma_f32_16x16x32_bf16(a, b, acc, 0, 0, 0);
            }
            #pragma unroll
            for (int r = 0; r < 4; ++r) {
                int tok = ms * 16 + 4 * q + r;
                int g = g0 + tok;
                unsigned short h = f2bf((acc[r] + bsc) * scl);
                if (matU < 2) {
                    dqk[(size_t)g * 64 + j] = h;
                } else {
                    int b = g >> 11, n = g & (N_ - 1);
                    int s = n >> 7,  t = n & (T_ - 1);
                    vbT[((size_t)b * 64 + j) * N_ + t * S_ + s] = h;   // vf quirk
                }
            }
        }
    }
}

// ---------------------------------------------------------------------------
// Kernel 2: fused masked-softmax attention.
// Block = 16 query rows (one s), 4 waves; wave w owns key cols [w*512,w*512+512).
// Single pass: S via MFMA (direct L2 frag loads), exp (no max-subtract: exact
// for this score range; masked -> exp(-1e9)=0), unnormalized exp stashed bf16
// in regs, PV via MFMA after wave-private LDS transpose, epilogue normalizes.
// Tag-mismatched 128-key tiles (one s' each) are skipped & zero-filled.
// ---------------------------------------------------------------------------
__global__ __launch_bounds__(256, 2) void attn_kernel(
    const unsigned short* __restrict__ qb,
    const unsigned short* __restrict__ kb,
    const unsigned short* __restrict__ vbT,
    const int*  __restrict__ tags,
    const float* __restrict__ mask,
    float* __restrict__ out)                 // [ctx 1048576 | p 33554432] f32
{
    __shared__ unsigned short plds[4][16][136];  // per-wave P transpose buffer
    __shared__ float ctxbuf[4][16][64];          // cross-wave ctx partials
    __shared__ unsigned maskcols[128];           // bit i = mask[t0+i][t'] != 0
    __shared__ float lsum[4][16];
    __shared__ float ltinv[16];

    const int tid = threadIdx.x;
    const int bb  = blockIdx.x >> 7;             // batch
    const int q0  = (blockIdx.x & 127) * 16;     // first query row (within batch)
    const int s   = q0 >> 7;
    const int t0  = q0 & (T_ - 1);

    if (tid < 128) {
        unsigned bits = 0;
        #pragma unroll
        for (int i = 0; i < 16; ++i)
            bits |= (mask[(t0 + i) * T_ + tid] != 0.0f ? 1u : 0u) << i;
        maskcols[tid] = bits;
    }
    __syncthreads();

    const int w = tid >> 6, lane = tid & 63;
    const int q = lane >> 4, l15 = lane & 15;
    const int col0w = w * 512;

    unsigned mbq[8];                             // 4 mask bits (rows 4q..4q+3) per nt
    #pragma unroll
    for (int nt = 0; nt < 8; ++nt)
        mbq[nt] = (maskcols[nt * 16 + l15] >> (4 * q)) & 0xFu;

    const int tg = tags[bb * S_ + s];

    // Q a-frags: reused across all key tiles
    const unsigned short* qrow = qb + ((size_t)bb * N_ + q0 + l15) * 64 + q * 8;
    const s16x8 aq0 = ldfrag_g(qrow);
    const s16x8 aq1 = ldfrag_g(qrow + 32);

    float ps[4] = {0.f, 0.f, 0.f, 0.f};          // per-lane row-sum partials
    f32x4 pvacc[4];
    #pragma unroll
    for (int nv = 0; nv < 4; ++nv) pvacc[nv] = (f32x4){0.f, 0.f, 0.f, 0.f};

    unsigned stash[4][16];                        // bf16x2-packed unnormalized exp
    bool validt[4];
    float* pbase = out + (size_t)(B_ * N_ * 64);  // p_attn region

    #pragma unroll
    for (int tile = 0; tile < 4; ++tile) {
        const int colT = col0w + tile * 128;
        const bool valid = (tags[bb * S_ + (colT >> 7)] == tg);
        validt[tile] = valid;
        if (valid) {
            f32x4 sacc[8];
            #pragma unroll
            for (int nt = 0; nt < 8; ++nt) sacc[nt] = (f32x4){0.f, 0.f, 0.f, 0.f};
            const unsigned short* kB =
                kb + ((size_t)bb * N_ + colT + l15) * 64 + q * 8;
            #pragma unroll
            for (int nt = 0; nt < 8; ++nt) {
                s16x8 b0 = ldfrag_g(kB + nt * (16 * 64));
                s16x8 b1 = ldfrag_g(kB + nt * (16 * 64) + 32);
                sacc[nt] = __builtin_amdgcn_mfma_f32_16x16x32_bf16(aq0, b0, sacc[nt], 0, 0, 0);
                sacc[nt] = __builtin_amdgcn_mfma_f32_16x16x32_bf16(aq1, b1, sacc[nt], 0, 0, 0);
            }
            #pragma unroll
            for (int nt = 0; nt < 8; ++nt) {
                float e[4];
                #pragma unroll
                for (int r = 0; r < 4; ++r) {
                    float sc = ((mbq[nt] >> r) & 1u) ? sacc[nt][r] : NEGV;
                    e[r] = __expf(sc);           // exp(-1e9) == 0 exactly
                    ps[r] += e[r];
                    plds[w][4 * q + r][nt * 16 + l15] = f2bf(e[r]);
                }
                stash[tile][nt * 2 + 0] = (unsigned)f2bf(e[0]) | ((unsigned)f2bf(e[1]) << 16);
                stash[tile][nt * 2 + 1] = (unsigned)f2bf(e[2]) | ((unsigned)f2bf(e[3]) << 16);
            }
        } else {
            // whole tile masked by tags: write zeros now (float4, coalesced)
            #pragma unroll
            for (int jj = 0; jj < 8; ++jj) {
                int idx = jj * 64 + lane;
                int row = idx >> 5, c4 = (idx & 31) * 4;
                float4 z = {0.f, 0.f, 0.f, 0.f};
                *(float4*)(pbase + ((size_t)bb * N_ + q0 + row) * N_ + colT + c4) = z;
            }
        }
        __syncthreads();   // uniform; makes wave-private P round-trip bulletproof
        if (valid) {
            #pragma unroll
            for (int ks = 0; ks < 4; ++ks) {
                s16x8 ap = ldfrag_l(&plds[w][l15][ks * 32 + q * 8]);  // A-layout
                #pragma unroll
                for (int nv = 0; nv < 4; ++nv) {
                    const unsigned short* vB =
                        vbT + ((size_t)bb * 64 + nv * 16 + l15) * N_ + colT + ks * 32 + q * 8;
                    s16x8 bv = ldfrag_g(vB);
                    pvacc[nv] = __builtin_amdgcn_mfma_f32_16x16x32_bf16(ap, bv, pvacc[nv], 0, 0, 0);
                }
            }
        }
    }

    // Row sums: reduce across the 16 lanes of each quad (cols) ...
    #pragma unroll
    for (int r = 0; r < 4; ++r) {
        float v = ps[r];
        v += __shfl_xor(v, 1);
        v += __shfl_xor(v, 2);
        v += __shfl_xor(v, 4);
        v += __shfl_xor(v, 8);
        ps[r] = v;
    }
    if (l15 == 0) {
        float4 pv = {ps[0], ps[1], ps[2], ps[3]};
        *(float4*)&lsum[w][4 * q] = pv;
    }
    #pragma unroll
    for (int nv = 0; nv < 4; ++nv)
        #pragma unroll
        for (int r = 0; r < 4; ++r)
            ctxbuf[w][4 * q + r][nv * 16 + l15] = pvacc[nv][r];
    __syncthreads();

    // ... then across waves
    float inv[4];
    #pragma unroll
    for (int r = 0; r < 4; ++r) {
        float lt = lsum[0][4 * q + r] + lsum[1][4 * q + r] +
                   lsum[2][4 * q + r] + lsum[3][4 * q + r];
        inv[r] = 1.0f / lt;
    }
    if (w == 0 && l15 == 0) {
        #pragma unroll
        for (int r = 0; r < 4; ++r) ltinv[4 * q + r] = inv[r];
    }

    // Normalize stash and write p_attn (valid tiles only; others already zeroed)
    #pragma unroll
    for (int tile = 0; tile < 4; ++tile) {
        if (!validt[tile]) continue;
        const int colT = col0w + tile * 128;
        float* prow = pbase + ((size_t)bb * N_ + q0 + 4 * q) * N_ + colT + l15;
        #pragma unroll
        for (int nt = 0; nt < 8; ++nt) {
            unsigned p01 = stash[tile][nt * 2 + 0];
            unsigned p23 = stash[tile][nt * 2 + 1];
            prow[0 * N_ + nt * 16] = bf2f((unsigned short)(p01 & 0xFFFFu)) * inv[0];
            prow[1 * N_ + nt * 16] = bf2f((unsigned short)(p01 >> 16))     * inv[1];
            prow[2 * N_ + nt * 16] = bf2f((unsigned short)(p23 & 0xFFFFu)) * inv[2];
            prow[3 * N_ + nt * 16] = bf2f((unsigned short)(p23 >> 16))     * inv[3];
        }
    }
    __syncthreads();

    // ctx: reduce 4-wave partials, scale by 1/l, coalesced store
    #pragma unroll
    for (int e = 0; e < 4; ++e) {
        int idx = tid + 256 * e;
        int row = idx >> 6, dv = idx & 63;
        float v = ctxbuf[0][row][dv] + ctxbuf[1][row][dv] +
                  ctxbuf[2][row][dv] + ctxbuf[3][row][dv];
        v *= ltinv[row];
        out[((size_t)bb * N_ + q0 + row) * 64 + dv] = v;
    }
}

extern "C" void kernel_launch(void* const* d_in, const int* in_sizes, int n_in,
                              void* d_out, int out_size, void* d_ws, size_t ws_size,
                              hipStream_t stream)
{
    (void)in_sizes; (void)n_in; (void)out_size; (void)ws_size;
    const float* x    = (const float*)d_in[0];
    const int*   tags = (const int*)  d_in[1];
    const float* mask = (const float*)d_in[2];
    const float* Wk   = (const float*)d_in[3];
    const float* bk   = (const float*)d_in[4];
    const float* Wq   = (const float*)d_in[5];
    const float* bq   = (const float*)d_in[6];
    const float* Wv   = (const float*)d_in[7];
    const float* bv   = (const float*)d_in[8];
    float* out = (float*)d_out;

    unsigned short* qbuf = (unsigned short*)d_ws;              // 2 MB
    unsigned short* kbuf = qbuf + (size_t)B_ * N_ * 64;        // 2 MB
    unsigned short* vbT  = kbuf + (size_t)B_ * N_ * 64;        // 2 MB

    hipLaunchKernelGGL(proj_kernel, dim3(256), dim3(256), 0, stream,
                       x, Wq, bq, Wk, bk, Wv, bv, qbuf, kbuf, vbT);
    hipLaunchKernelGGL(attn_kernel, dim3(B_ * (N_ / 16)), dim3(256), 0, stream,
                       qbuf, kbuf, vbT, tags, mask, out);
}

// Round 2
// 192.837 us; speedup vs baseline: 1.0306x; 1.0306x over previous
//
#include <hip/hip_runtime.h>
#include <stdint.h>

// Problem constants (fixed by setup_inputs)
#define B_   8
#define S_   16
#define T_   128
#define D_   64
#define N_   2048               // S_*T_ tokens per batch
#define NEGV (-1000000000.0f)

typedef short s16x8 __attribute__((ext_vector_type(8)));   // 8 bf16 (4 VGPRs)
typedef float f32x4 __attribute__((ext_vector_type(4)));

static __device__ __forceinline__ unsigned short f2bf(float f) {
    unsigned u = __builtin_bit_cast(unsigned, f);
    u += 0x7FFFu + ((u >> 16) & 1u);            // RTNE
    return (unsigned short)(u >> 16);
}
static __device__ __forceinline__ float bf2f(unsigned short h) {
    unsigned u = ((unsigned)h) << 16;
    return __builtin_bit_cast(float, u);
}
static __device__ __forceinline__ s16x8 ldfrag_g(const unsigned short* p) {
    uint4 v = *(const uint4*)p;                 // global_load_dwordx4
    return __builtin_bit_cast(s16x8, v);
}
static __device__ __forceinline__ s16x8 ldfrag_l(const unsigned short* p) {
    uint4 v = *(const uint4*)p;                 // ds_read_b128
    return __builtin_bit_cast(s16x8, v);
}

// ---------------------------------------------------------------------------
// Kernel 1: QKV projection. x[f32] -> qb (scaled by 1/8), kb  [b][n][64] bf16,
// and v stored TRANSPOSED in the reference's quirky vf layout:
// vbT[b][dv][m], m = t*S + s  (so PV B-frags are contiguous 16B reads).
// One block = 64 tokens; MFMA 16x16x32 over concatenated W (q,k,v).
// ---------------------------------------------------------------------------
__global__ __launch_bounds__(256, 2) void proj_kernel(
    const float* __restrict__ x,
    const float* __restrict__ Wq, const float* __restrict__ bq,
    const float* __restrict__ Wk, const float* __restrict__ bk,
    const float* __restrict__ Wv, const float* __restrict__ bv,
    unsigned short* __restrict__ qb, unsigned short* __restrict__ kb,
    unsigned short* __restrict__ vbT)
{
    __shared__ unsigned short xs[64][72];    // +8 pad: conflict-light b128 reads
    __shared__ unsigned short Wl[192][72];   // rows: 0-63 Wq[j][i], 64-127 Wk, 128-191 Wv
    __shared__ float          biasl[192];

    const int tid = threadIdx.x;
    const int g0  = blockIdx.x * 64;         // first global token of block

    // Stage x tile (64x64 f32 -> bf16)
    const float4* xsrc = (const float4*)(x + (size_t)g0 * 64);
    #pragma unroll
    for (int k2 = 0; k2 < 4; ++k2) {
        int idx = tid + 256 * k2;            // float4 index, coalesced
        float4 v = xsrc[idx];
        int tok = idx >> 4, i4 = (idx & 15) * 4;
        uint2 pk;
        pk.x = (unsigned)f2bf(v.x) | ((unsigned)f2bf(v.y) << 16);
        pk.y = (unsigned)f2bf(v.z) | ((unsigned)f2bf(v.w) << 16);
        *(uint2*)&xs[tok][i4] = pk;
    }
    // Stage W (q,k,v) as-given layout [j][i] (this IS the B-frag-friendly layout)
    #pragma unroll
    for (int k2 = 0; k2 < 12; ++k2) {
        const float* wsrc = (k2 < 4) ? Wq : ((k2 < 8) ? Wk : Wv);
        int f4i = (k2 & 3) * 256 + tid;
        float4 v = ((const float4*)wsrc)[f4i];
        int j = f4i >> 4, i4 = (f4i & 15) * 4;
        int row = (k2 >> 2) * 64 + j;
        uint2 pk;
        pk.x = (unsigned)f2bf(v.x) | ((unsigned)f2bf(v.y) << 16);
        pk.y = (unsigned)f2bf(v.z) | ((unsigned)f2bf(v.w) << 16);
        *(uint2*)&Wl[row][i4] = pk;
    }
    if (tid < 192) {
        int m = tid >> 6;
        const float* bs = (m == 0) ? bq : (m == 1 ? bk : bv);
        biasl[tid] = bs[tid & 63];
    }
    __syncthreads();

    const int w = tid >> 6, lane = tid & 63;
    const int q = lane >> 4, l15 = lane & 15;

    #pragma unroll
    for (int e = 0; e < 3; ++e) {
        const int nt   = w * 3 + e;          // 12 N-subtiles of 16 across q|k|v
        const int matU = nt >> 2;            // 0=q 1=k 2=v (16 | 64, never splits)
        const float bsc = biasl[nt * 16 + l15];
        const float scl = (matU == 0) ? 0.125f : 1.0f;   // fold 1/sqrt(64) into q
        const int j = (nt & 3) * 16 + l15;   // output dim within its matrix
        unsigned short* dqk = (matU == 0) ? qb : kb;
        #pragma unroll
        for (int ms = 0; ms < 4; ++ms) {
            f32x4 acc = {0.f, 0.f, 0.f, 0.f};
            #pragma unroll
            for (int ks = 0; ks < 2; ++ks) {
                s16x8 a = ldfrag_l(&xs[ms * 16 + l15][ks * 32 + q * 8]);
                s16x8 b = ldfrag_l(&Wl[nt * 16 + l15][ks * 32 + q * 8]);
                acc = __builtin_amdgcn_mfma_f32_16x16x32_bf16(a, b, acc, 0, 0, 0);
            }
            #pragma unroll
            for (int r = 0; r < 4; ++r) {
                int tok = ms * 16 + 4 * q + r;
                int g = g0 + tok;
                unsigned short h = f2bf((acc[r] + bsc) * scl);
                if (matU < 2) {
                    dqk[(size_t)g * 64 + j] = h;
                } else {
                    int b = g >> 11, n = g & (N_ - 1);
                    int s = n >> 7,  t = n & (T_ - 1);
                    vbT[((size_t)b * 64 + j) * N_ + t * S_ + s] = h;   // vf quirk
                }
            }
        }
    }
}

// ---------------------------------------------------------------------------
// Kernel 2: fused masked-softmax attention.
// Block = 16 query rows (one s), 4 waves; wave w owns key cols [w*512,w*512+512).
// Tile loop is barrier-free (plds is wave-private; wave-internal LDS ordering
// suffices). Epilogue transposes stashed bf16 exp via plds and writes p_attn
// with float4 coalesced stores (512B contiguous per half-wave).
// ---------------------------------------------------------------------------
__global__ __launch_bounds__(256, 2) void attn_kernel(
    const unsigned short* __restrict__ qb,
    const unsigned short* __restrict__ kb,
    const unsigned short* __restrict__ vbT,
    const int*  __restrict__ tags,
    const float* __restrict__ mask,
    float* __restrict__ out)                 // [ctx 1048576 | p 33554432] f32
{
    __shared__ unsigned short plds[4][16][138];  // per-wave P transpose buffer (+2 pad)
    __shared__ float ctxbuf[4][16][64];          // cross-wave ctx partials
    __shared__ unsigned maskcols[128];           // bit i = mask[t0+i][t'] != 0
    __shared__ float lsum[4][16];
    __shared__ float ltinv[16];

    const int tid = threadIdx.x;
    const int bb  = blockIdx.x >> 7;             // batch
    const int q0  = (blockIdx.x & 127) * 16;     // first query row (within batch)
    const int s   = q0 >> 7;
    const int t0  = q0 & (T_ - 1);

    if (tid < 128) {
        unsigned bits = 0;
        #pragma unroll
        for (int i = 0; i < 16; ++i)
            bits |= (mask[(t0 + i) * T_ + tid] != 0.0f ? 1u : 0u) << i;
        maskcols[tid] = bits;
    }
    __syncthreads();

    const int w = tid >> 6, lane = tid & 63;
    const int q = lane >> 4, l15 = lane & 15;
    const int col0w = w * 512;

    unsigned mbq[8];                             // 4 mask bits (rows 4q..4q+3) per nt
    #pragma unroll
    for (int nt = 0; nt < 8; ++nt)
        mbq[nt] = (maskcols[nt * 16 + l15] >> (4 * q)) & 0xFu;

    const int tg = tags[bb * S_ + s];

    // Q a-frags: reused across all key tiles
    const unsigned short* qrow = qb + ((size_t)bb * N_ + q0 + l15) * 64 + q * 8;
    const s16x8 aq0 = ldfrag_g(qrow);
    const s16x8 aq1 = ldfrag_g(qrow + 32);

    float ps[4] = {0.f, 0.f, 0.f, 0.f};          // per-lane row-sum partials
    f32x4 pvacc[4];
    #pragma unroll
    for (int nv = 0; nv < 4; ++nv) pvacc[nv] = (f32x4){0.f, 0.f, 0.f, 0.f};

    unsigned stash[4][16];                        // bf16x2-packed unnormalized exp
    bool validt[4];
    float* pbase = out + (size_t)(B_ * N_ * 64);  // p_attn region

    #pragma unroll
    for (int tile = 0; tile < 4; ++tile) {
        const int colT = col0w + tile * 128;
        const bool valid = (tags[bb * S_ + (colT >> 7)] == tg);
        validt[tile] = valid;
        if (!valid) continue;                     // zeros handled in epilogue

        f32x4 sacc[8];
        #pragma unroll
        for (int nt = 0; nt < 8; ++nt) sacc[nt] = (f32x4){0.f, 0.f, 0.f, 0.f};
        const unsigned short* kB =
            kb + ((size_t)bb * N_ + colT + l15) * 64 + q * 8;
        #pragma unroll
        for (int nt = 0; nt < 8; ++nt) {
            s16x8 b0 = ldfrag_g(kB + nt * (16 * 64));
            s16x8 b1 = ldfrag_g(kB + nt * (16 * 64) + 32);
            sacc[nt] = __builtin_amdgcn_mfma_f32_16x16x32_bf16(aq0, b0, sacc[nt], 0, 0, 0);
            sacc[nt] = __builtin_amdgcn_mfma_f32_16x16x32_bf16(aq1, b1, sacc[nt], 0, 0, 0);
        }
        #pragma unroll
        for (int nt = 0; nt < 8; ++nt) {
            float e[4];
            unsigned short h[4];
            #pragma unroll
            for (int r = 0; r < 4; ++r) {
                float sc = ((mbq[nt] >> r) & 1u) ? sacc[nt][r] : NEGV;
                e[r] = __expf(sc);           // exp(-1e9) == 0 exactly
                ps[r] += e[r];
                h[r] = f2bf(e[r]);
                plds[w][4 * q + r][nt * 16 + l15] = h[r];
            }
            stash[tile][nt * 2 + 0] = (unsigned)h[0] | ((unsigned)h[1] << 16);
            stash[tile][nt * 2 + 1] = (unsigned)h[2] | ((unsigned)h[3] << 16);
        }
        // PV: wave-private LDS round-trip (C-layout -> A-layout); no barrier
        // needed — LDS ops within a wave are ordered, compiler inserts lgkmcnt.
        #pragma unroll
        for (int ks = 0; ks < 4; ++ks) {
            s16x8 ap = ldfrag_l(&plds[w][l15][ks * 32 + q * 8]);  // A-layout
            #pragma unroll
            for (int nv = 0; nv < 4; ++nv) {
                const unsigned short* vB =
                    vbT + ((size_t)bb * 64 + nv * 16 + l15) * N_ + colT + ks * 32 + q * 8;
                s16x8 bv = ldfrag_g(vB);
                pvacc[nv] = __builtin_amdgcn_mfma_f32_16x16x32_bf16(ap, bv, pvacc[nv], 0, 0, 0);
            }
        }
    }

    // Row sums: reduce across the 16 lanes of each quad (cols) ...
    #pragma unroll
    for (int r = 0; r < 4; ++r) {
        float v = ps[r];
        v += __shfl_xor(v, 1);
        v += __shfl_xor(v, 2);
        v += __shfl_xor(v, 4);
        v += __shfl_xor(v, 8);
        ps[r] = v;
    }
    if (l15 == 0) {
        float4 pv = {ps[0], ps[1], ps[2], ps[3]};
        *(float4*)&lsum[w][4 * q] = pv;
    }
    #pragma unroll
    for (int nv = 0; nv < 4; ++nv)
        #pragma unroll
        for (int r = 0; r < 4; ++r)
            ctxbuf[w][4 * q + r][nv * 16 + l15] = pvacc[nv][r];
    __syncthreads();

    // ... then across waves: one lane per row computes 1/l
    if (tid < 16) {
        float lt = lsum[0][tid] + lsum[1][tid] + lsum[2][tid] + lsum[3][tid];
        ltinv[tid] = 1.0f / lt;
    }
    __syncthreads();

    // Epilogue: normalize + write p_attn with coalesced float4 stores.
    // Valid tiles: stash -> plds (bf16 transpose), read back row-major.
    #pragma unroll
    for (int tile = 0; tile < 4; ++tile) {
        const int colT = col0w + tile * 128;
        if (validt[tile]) {
            #pragma unroll
            for (int nt = 0; nt < 8; ++nt) {
                unsigned p01 = stash[tile][nt * 2 + 0];
                unsigned p23 = stash[tile][nt * 2 + 1];
                plds[w][4 * q + 0][nt * 16 + l15] = (unsigned short)(p01 & 0xFFFFu);
                plds[w][4 * q + 1][nt * 16 + l15] = (unsigned short)(p01 >> 16);
                plds[w][4 * q + 2][nt * 16 + l15] = (unsigned short)(p23 & 0xFFFFu);
                plds[w][4 * q + 3][nt * 16 + l15] = (unsigned short)(p23 >> 16);
            }
            #pragma unroll
            for (int j = 0; j < 8; ++j) {
                int idx = j * 64 + lane;              // 0..511
                int row = idx >> 5;                   // 0..15
                int c4  = (idx & 31) * 4;             // 0..124
                uint2 hv = *(const uint2*)&plds[w][row][c4];  // ds_read_b64
                float iv = ltinv[row];
                float4 o;
                o.x = bf2f((unsigned short)(hv.x & 0xFFFFu)) * iv;
                o.y = bf2f((unsigned short)(hv.x >> 16))     * iv;
                o.z = bf2f((unsigned short)(hv.y & 0xFFFFu)) * iv;
                o.w = bf2f((unsigned short)(hv.y >> 16))     * iv;
                *(float4*)(pbase + ((size_t)bb * N_ + q0 + row) * N_ + colT + c4) = o;
            }
        } else {
            #pragma unroll
            for (int j = 0; j < 8; ++j) {
                int idx = j * 64 + lane;
                int row = idx >> 5, c4 = (idx & 31) * 4;
                float4 z = {0.f, 0.f, 0.f, 0.f};
                *(float4*)(pbase + ((size_t)bb * N_ + q0 + row) * N_ + colT + c4) = z;
            }
        }
    }

    // ctx: reduce 4-wave partials, scale by 1/l, coalesced store
    #pragma unroll
    for (int e = 0; e < 4; ++e) {
        int idx = tid + 256 * e;
        int row = idx >> 6, dv = idx & 63;
        float v = ctxbuf[0][row][dv] + ctxbuf[1][row][dv] +
                  ctxbuf[2][row][dv] + ctxbuf[3][row][dv];
        v *= ltinv[row];
        out[((size_t)bb * N_ + q0 + row) * 64 + dv] = v;
    }
}

extern "C" void kernel_launch(void* const* d_in, const int* in_sizes, int n_in,
                              void* d_out, int out_size, void* d_ws, size_t ws_size,
                              hipStream_t stream)
{
    (void)in_sizes; (void)n_in; (void)out_size; (void)ws_size;
    const float* x    = (const float*)d_in[0];
    const int*   tags = (const int*)  d_in[1];
    const float* mask = (const float*)d_in[2];
    const float* Wk   = (const float*)d_in[3];
    const float* bk   = (const float*)d_in[4];
    const float* Wq   = (const float*)d_in[5];
    const float* bq   = (const float*)d_in[6];
    const float* Wv   = (const float*)d_in[7];
    const float* bv   = (const float*)d_in[8];
    float* out = (float*)d_out;

    unsigned short* qbuf = (unsigned short*)d_ws;              // 2 MB
    unsigned short* kbuf = qbuf + (size_t)B_ * N_ * 64;        // 2 MB
    unsigned short* vbT  = kbuf + (size_t)B_ * N_ * 64;        // 2 MB

    hipLaunchKernelGGL(proj_kernel, dim3(256), dim3(256), 0, stream,
                       x, Wq, bq, Wk, bk, Wv, bv, qbuf, kbuf, vbT);
    hipLaunchKernelGGL(attn_kernel, dim3(B_ * (N_ / 16)), dim3(256), 0, stream,
                       qbuf, kbuf, vbT, tags, mask, out);
}